// Round 1
// baseline (928.436 us; speedup 1.0000x reference)
//
#include <hip/hip_runtime.h>
#include <stdint.h>

// Problem constants (EdgeEncoder_28071906247258)
#define BB 4
#define NN 100000
#define DD 128
#define EE 262144   // 2^18 edges per batch
#define HH 128
#define OO 128

typedef __attribute__((ext_vector_type(4))) float f32x4;
typedef __attribute__((ext_vector_type(8))) __bf16 bf16x8;

static __device__ __forceinline__ unsigned short f2bf(float f) {
    union { float f; unsigned u; } v; v.f = f;
    return (unsigned short)((v.u + 0x7fffu + ((v.u >> 16) & 1u)) >> 16);  // RNE
}

// ---------------------------------------------------------------------------
// Prep: swizzle W1 rows 0..255 (fp32 [257][128]) into bf16 B-fragment order:
//   frag(kt,nt): lane holds W1[k = kt*32 + (lane>>4)*8 + j][n = nt*16 + (lane&15)]
//   flat ushort index = ((kt*8+nt)*64 + lane)*8 + j        (64 KB total)
// ---------------------------------------------------------------------------
__global__ __launch_bounds__(256) void prep_w1(const float* __restrict__ W1,
                                               unsigned short* __restrict__ w1f) {
    int t = blockIdx.x * 256 + threadIdx.x;
    if (t >= 256 * 128) return;
    int k = t >> 7, n = t & 127;
    int kt = k >> 5, quad = (k >> 3) & 3, j = k & 7;
    int nt = n >> 4, nl = n & 15;
    int f = ((((kt * 8 + nt) * 64) + quad * 16 + nl) << 3) | j;
    w1f[f] = f2bf(W1[t]);
}

// ---------------------------------------------------------------------------
// Fused edge MLP: gather u,v -> layer1 MFMA -> (+sel*w1c +b1, relu) ->
// LDS transpose -> layer2 MFMA -> (+b2, relu) -> store.
// Block = 256 threads = 4 waves; each wave owns 64 edges (4 M-tiles of 16).
// ---------------------------------------------------------------------------
__global__ __launch_bounds__(256, 2) void edge_mlp(
    const float* __restrict__ node_emb,
    const int* __restrict__ edge_index,
    const float* __restrict__ edge_sel,
    const float* __restrict__ W1,
    const float* __restrict__ b1,
    const float* __restrict__ W2,
    const float* __restrict__ b2,
    const unsigned short* __restrict__ w1f,
    float* __restrict__ out)
{
    __shared__ unsigned short w2f[16384];      // 32 KB: W2 frags, same order as w1f
    __shared__ unsigned short hst[4][16 * 136]; // per-wave h tile, pad 136 (2-way = free)

    const int tid = threadIdx.x;

    // Build W2 fragment LDS (coalesced global reads, scattered 2B LDS writes)
    for (int s = tid; s < 16384; s += 256) {
        int k = s >> 7, n = s & 127;
        int f = ((((k >> 5) * 8 + (n >> 4)) * 64) + ((k >> 3) & 3) * 16 + (n & 15)) * 8 + (k & 7);
        w2f[f] = f2bf(W2[s]);
    }
    __syncthreads();

    const int lane = tid & 63;
    const int wv = tid >> 6;
    const int nl = lane & 15;     // column lane / A-row lane
    const int quad = lane >> 4;   // 0..3

    // Per-lane epilogue constants: col = nt*16 + nl
    float b1v[8], w1cv[8], b2v[8];
#pragma unroll
    for (int nt = 0; nt < 8; ++nt) {
        b1v[nt] = b1[nt * 16 + nl];
        w1cv[nt] = W1[256 * 128 + nt * 16 + nl];  // W1 row 256 = sel weights
        b2v[nt] = b2[nt * 16 + nl];
    }

    const int eb = blockIdx.x * 256 + wv * 64;  // global edge base of this wave
    const int bat = eb >> 18;                   // / EE
    const size_t nbase = (size_t)bat * NN * DD;

    // Gather row offsets: lane's A-row edge = eb + mt*16 + nl
    unsigned ou[4], ov[4];
#pragma unroll
    for (int mt = 0; mt < 4; ++mt) {
        int e = eb + mt * 16 + nl;
        int iu = edge_index[(size_t)e * 2 + 0];
        int iv = edge_index[(size_t)e * 2 + 1];
        iu = min(max(iu, 0), NN - 1);
        iv = min(max(iv, 0), NN - 1);
        ou[mt] = (unsigned)nbase + (unsigned)iu * DD + quad * 8;
        ov[mt] = (unsigned)nbase + (unsigned)iv * DD + quad * 8;
    }

    // ---- Layer 1: acc[mt][nt] = X[16x256] * W1[256x128] ----
    f32x4 acc[4][8];
#pragma unroll
    for (int mt = 0; mt < 4; ++mt)
#pragma unroll
        for (int nt = 0; nt < 8; ++nt)
            acc[mt][nt] = f32x4{0.f, 0.f, 0.f, 0.f};

    const bf16x8* wbase = (const bf16x8*)w1f;
#pragma unroll
    for (int kt = 0; kt < 8; ++kt) {
        bf16x8 af[4];
#pragma unroll
        for (int mt = 0; mt < 4; ++mt) {
            unsigned o = ((kt < 4) ? ou[mt] : ov[mt]) + (kt & 3) * 32;
            f32x4 x0 = *(const f32x4*)(node_emb + o);
            f32x4 x1 = *(const f32x4*)(node_emb + o + 4);
            bf16x8 a;
            a[0] = (__bf16)x0[0]; a[1] = (__bf16)x0[1];
            a[2] = (__bf16)x0[2]; a[3] = (__bf16)x0[3];
            a[4] = (__bf16)x1[0]; a[5] = (__bf16)x1[1];
            a[6] = (__bf16)x1[2]; a[7] = (__bf16)x1[3];
            af[mt] = a;
        }
#pragma unroll
        for (int nt = 0; nt < 8; ++nt) {
            bf16x8 bf = wbase[(kt * 8 + nt) * 64 + lane];
#pragma unroll
            for (int mt = 0; mt < 4; ++mt)
                acc[mt][nt] = __builtin_amdgcn_mfma_f32_16x16x32_bf16(af[mt], bf, acc[mt][nt], 0, 0, 0);
        }
    }

    // ---- Epilogue 1 + transpose + Layer 2 (M-tile pairs) ----
    const bf16x8* w2base = (const bf16x8*)w2f;
    unsigned short* hw = hst[wv];

#pragma unroll
    for (int pr = 0; pr < 2; ++pr) {
        bf16x8 ha[2][4];
#pragma unroll
        for (int q = 0; q < 2; ++q) {
            const int mt = pr * 2 + q;
            // sel for the 4 C-layout rows this lane owns
            float sel[4];
#pragma unroll
            for (int i = 0; i < 4; ++i)
                sel[i] = edge_sel[(size_t)(eb + mt * 16 + quad * 4 + i)];
            // h = relu(acc + sel*w1c + b1), write C-layout into LDS tile
#pragma unroll
            for (int nt = 0; nt < 8; ++nt) {
#pragma unroll
                for (int i = 0; i < 4; ++i) {
                    float hv = acc[mt][nt][i] + sel[i] * w1cv[nt] + b1v[nt];
                    hv = fmaxf(hv, 0.f);
                    hw[(quad * 4 + i) * 136 + nt * 16 + nl] = f2bf(hv);
                }
            }
            __syncthreads();  // writes visible (uniform across waves)
            // read back in A-operand layout: h[m=nl][k=kt2*32+quad*8+j]
#pragma unroll
            for (int kt2 = 0; kt2 < 4; ++kt2)
                ha[q][kt2] = *(const bf16x8*)(hw + nl * 136 + kt2 * 32 + quad * 8);
            __syncthreads();  // reads done before tile is overwritten
        }

        f32x4 a2[2][8];
#pragma unroll
        for (int q = 0; q < 2; ++q)
#pragma unroll
            for (int nt = 0; nt < 8; ++nt)
                a2[q][nt] = f32x4{0.f, 0.f, 0.f, 0.f};

#pragma unroll
        for (int kt2 = 0; kt2 < 4; ++kt2) {
#pragma unroll
            for (int nt = 0; nt < 8; ++nt) {
                bf16x8 bf = w2base[(kt2 * 8 + nt) * 64 + lane];
                a2[0][nt] = __builtin_amdgcn_mfma_f32_16x16x32_bf16(ha[0][kt2], bf, a2[0][nt], 0, 0, 0);
                a2[1][nt] = __builtin_amdgcn_mfma_f32_16x16x32_bf16(ha[1][kt2], bf, a2[1][nt], 0, 0, 0);
            }
        }

        // ---- Epilogue 2: relu(a2 + b2) -> out (C-layout store, 64B/quad segs)
#pragma unroll
        for (int q = 0; q < 2; ++q) {
            const int mt = pr * 2 + q;
#pragma unroll
            for (int nt = 0; nt < 8; ++nt) {
#pragma unroll
                for (int i = 0; i < 4; ++i) {
                    float o = a2[q][nt][i] + b2v[nt];
                    o = fmaxf(o, 0.f);
                    out[(size_t)(eb + mt * 16 + quad * 4 + i) * OO + nt * 16 + nl] = o;
                }
            }
        }
    }
}

extern "C" void kernel_launch(void* const* d_in, const int* in_sizes, int n_in,
                              void* d_out, int out_size, void* d_ws, size_t ws_size,
                              hipStream_t stream) {
    const float* node_emb  = (const float*)d_in[0];
    const int*   edge_index= (const int*)d_in[1];
    const float* edge_sel  = (const float*)d_in[2];
    const float* W1        = (const float*)d_in[3];
    const float* b1        = (const float*)d_in[4];
    const float* W2        = (const float*)d_in[5];
    const float* b2        = (const float*)d_in[6];
    unsigned short* w1f    = (unsigned short*)d_ws;  // 64 KB W1 fragment buffer
    float* out             = (float*)d_out;

    prep_w1<<<dim3(128), dim3(256), 0, stream>>>(W1, w1f);
    // 4096 blocks * 256 edges/block = 1,048,576 edges, exact (EE % 256 == 0)
    edge_mlp<<<dim3(4096), dim3(256), 0, stream>>>(node_emb, edge_index, edge_sel,
                                                   W1, b1, W2, b2, w1f, out);
}